// Round 3
// baseline (1396.214 us; speedup 1.0000x reference)
//
#include <hip/hip_runtime.h>

#define NB_ 3
#define CB 4
#define CH 1440
#define CW 1440
#define NC 32
#define EPSV 1e-3f

// ---------------- kernel 1: build idx_map via atomicMax (numpy last-write-wins) ----
__global__ __launch_bounds__(256) void k_build_map(
    const int* __restrict__ cb, const int* __restrict__ cy, const int* __restrict__ cx,
    int* __restrict__ idx_map, int n)
{
    int i = blockIdx.x * blockDim.x + threadIdx.x;
    if (i < n) {
        long cell = ((long)cb[i] * CH + cy[i]) * CW + cx[i];
        atomicMax(&idx_map[cell], i);
    }
}

// ---------------- kernel 2: rulebook. meta[p]={selfidx,cnt}; rbent: non-self only --
__global__ __launch_bounds__(256) void k_rulebook(
    const int* __restrict__ cb, const int* __restrict__ cy, const int* __restrict__ cx,
    const int* __restrict__ idx_map, int2* __restrict__ meta, int* __restrict__ rbent, int n)
{
    int i = blockIdx.x * blockDim.x + threadIdx.x;
    if (i >= n) return;
    int b = cb[i], y = cy[i], x = cx[i];
    int s = idx_map[((long)b * CH + y) * CW + x];   // may differ from i on dup coords
    int cnt = 0;
    int base = i * 8;
    #pragma unroll
    for (int k = 0; k < 9; ++k) {
        if (k == 4) continue;
        int dy = k / 3 - 1, dx = k % 3 - 1;
        int ny = y + dy, nx = x + dx;
        if (ny >= 0 && ny < CH && nx >= 0 && nx < CW) {
            int nb = idx_map[((long)b * CH + ny) * CW + nx];
            if (nb >= 0) {
                int kk = (k < 4) ? k : k - 1;       // compacted 0..7 (skip self)
                rbent[base + cnt] = (nb << 3) | kk;
                ++cnt;
            }
        }
    }
    meta[i] = make_int2(s, cnt);
}

// ---------------- kernel 3: sparse conv + fused BN (+identity) + ReLU ---------------
// lane = output channel o; half-wave owns 2 points (4 pts/wave, 16/block-iter).
// Self (k=4) W column held in 32 VGPRs -> dense GEMV, no LDS at all.
// Rare non-self entries read their W row via broadcast global loads (L2-hot, 36KB).
// No LDS -> occupancy capped only by VGPR: 64 VGPR -> 8 waves/SIMD -> 32 waves/CU.
template<bool ADD_ID>
__global__ __launch_bounds__(256, 8) void k_conv(
    const float* __restrict__ in, const float* __restrict__ idn, float* __restrict__ out,
    const float* __restrict__ W,      // [9][32][32] (k,c,o)
    const float* __restrict__ bias,
    const float* __restrict__ gamma, const float* __restrict__ beta,
    const float* __restrict__ mean, const float* __restrict__ var,
    const int2* __restrict__ meta, const int* __restrict__ rbent, int n)
{
    int o = threadIdx.x & 31;

    // self weight column in registers: w4[c] = W[4][c][o]
    float w4[32];
    #pragma unroll
    for (int c = 0; c < 32; ++c) w4[c] = W[4 * 1024 + c * 32 + o];

    int half = (threadIdx.x >> 5) & 1;
    int waveid = threadIdx.x >> 6;
    int unit = waveid * 2 + half;          // 0..7

    float sc = gamma[o] * rsqrtf(var[o] + EPSV);
    float sh = (bias[o] - mean[o]) * sc + beta[o];

    const int PPB = 16;
    for (int p0 = blockIdx.x * PPB; p0 < n; p0 += gridDim.x * PPB) {
        int pA = p0 + unit * 2;
        int pB = pA + 1;
        bool vA = pA < n, vB = pB < n;

        int2 mA = vA ? meta[pA] : make_int2(0, 0);
        int2 mB = vB ? meta[pB] : make_int2(0, 0);

        const float4* xpA = (const float4*)(in + (size_t)mA.x * NC);
        const float4* xpB = (const float4*)(in + (size_t)mB.x * NC);

        float accA = 0.f, accB = 0.f;
        #pragma unroll
        for (int j = 0; j < 8; ++j) {
            float4 a = vA ? xpA[j] : make_float4(0, 0, 0, 0);
            float4 b = vB ? xpB[j] : make_float4(0, 0, 0, 0);
            accA += a.x * w4[4*j] + a.y * w4[4*j+1] + a.z * w4[4*j+2] + a.w * w4[4*j+3];
            accB += b.x * w4[4*j] + b.y * w4[4*j+1] + b.z * w4[4*j+2] + b.w * w4[4*j+3];
        }

        // rare neighbor entries (W rows via broadcast global loads, L2-hot)
        for (int e = 0; e < mA.y; ++e) {
            int en = rbent[pA * 8 + e];
            int kk = en & 7, idx = en >> 3;
            int k = (kk < 4) ? kk : kk + 1;
            const float4* xp = (const float4*)(in + (size_t)idx * NC);
            const float*  wc = W + k * 1024 + o;
            #pragma unroll
            for (int j = 0; j < 8; ++j) {
                float4 xv = xp[j];
                accA += xv.x * wc[(4*j+0)*32] + xv.y * wc[(4*j+1)*32]
                      + xv.z * wc[(4*j+2)*32] + xv.w * wc[(4*j+3)*32];
            }
        }
        for (int e = 0; e < mB.y; ++e) {
            int en = rbent[pB * 8 + e];
            int kk = en & 7, idx = en >> 3;
            int k = (kk < 4) ? kk : kk + 1;
            const float4* xp = (const float4*)(in + (size_t)idx * NC);
            const float*  wc = W + k * 1024 + o;
            #pragma unroll
            for (int j = 0; j < 8; ++j) {
                float4 xv = xp[j];
                accB += xv.x * wc[(4*j+0)*32] + xv.y * wc[(4*j+1)*32]
                      + xv.z * wc[(4*j+2)*32] + xv.w * wc[(4*j+3)*32];
            }
        }

        if (vA) {
            float y = accA * sc + sh;
            if (ADD_ID) y += idn[(size_t)pA * NC + o];
            out[(size_t)pA * NC + o] = fmaxf(y, 0.f);
        }
        if (vB) {
            float y = accB * sc + sh;
            if (ADD_ID) y += idn[(size_t)pB * NC + o];
            out[(size_t)pB * NC + o] = fmaxf(y, 0.f);
        }
    }
}

extern "C" void kernel_launch(void* const* d_in, const int* in_sizes, int n_in,
                              void* d_out, int out_size, void* d_ws, size_t ws_size,
                              hipStream_t stream)
{
    const float* feats = (const float*)d_in[0];
    const float* Wk    = (const float*)d_in[1];  // [3][2][9][32][32]
    const float* bias  = (const float*)d_in[2];
    const float* gamma = (const float*)d_in[3];
    const float* beta  = (const float*)d_in[4];
    const float* mean  = (const float*)d_in[5];
    const float* var   = (const float*)d_in[6];
    const int* cb = (const int*)d_in[7];
    const int* cy = (const int*)d_in[8];
    const int* cx = (const int*)d_in[9];
    float* out = (float*)d_out;
    int n = in_sizes[0] / NC;

    char* ws = (char*)d_ws;
    int*   idx_map = (int*)(ws + 0);                       // 33,177,600 B
    int2*  meta    = (int2*)(ws + 33177600);               // 1,600,000 B
    int*   rbent   = (int*)(ws + 34777600);                // 6,400,000 B
    float* tmp     = (float*)(ws + 41177600);              // 25,600,000 B
    float* hbuf    = (float*)(ws + 66777600);              // 25,600,000 B

    hipMemsetAsync(idx_map, 0xFF, (size_t)CB * CH * CW * sizeof(int), stream);

    int blocks = (n + 255) / 256;
    k_build_map<<<blocks, 256, 0, stream>>>(cb, cy, cx, idx_map, n);
    k_rulebook<<<blocks, 256, 0, stream>>>(cb, cy, cx, idx_map, meta, rbent, n);

    const int CONV_GRID = 2048; // 8 blocks/CU (VGPR-limited, no LDS)
    const float* hin = feats;
    for (int i = 0; i < NB_; ++i) {
        int l1 = i * 2 + 0, l2 = i * 2 + 1;
        k_conv<false><<<CONV_GRID, 256, 0, stream>>>(
            hin, nullptr, tmp,
            Wk + (size_t)l1 * 9 * 32 * 32, bias + l1 * 32,
            gamma + l1 * 32, beta + l1 * 32, mean + l1 * 32, var + l1 * 32,
            meta, rbent, n);
        float* outp = (i == NB_ - 1) ? out : hbuf;
        k_conv<true><<<CONV_GRID, 256, 0, stream>>>(
            tmp, hin, outp,
            Wk + (size_t)l2 * 9 * 32 * 32, bias + l2 * 32,
            gamma + l2 * 32, beta + l2 * 32, mean + l2 * 32, var + l2 * 32,
            meta, rbent, n);
        hin = (i == NB_ - 1) ? out : hbuf;
    }
}

// Round 4
// 394.993 us; speedup vs baseline: 3.5348x; 3.5348x over previous
//
#include <hip/hip_runtime.h>

#define NB_ 3
#define CB 4
#define CH 1440
#define CW 1440
#define NC 32
#define EPSV 1e-3f

// ---------------- kernel 1: build idx_map via atomicMax (numpy last-write-wins) ----
__global__ __launch_bounds__(256) void k_build_map(
    const int* __restrict__ cb, const int* __restrict__ cy, const int* __restrict__ cx,
    int* __restrict__ idx_map, int n)
{
    int i = blockIdx.x * blockDim.x + threadIdx.x;
    if (i < n) {
        long cell = ((long)cb[i] * CH + cy[i]) * CW + cx[i];
        atomicMax(&idx_map[cell], i);
    }
}

// ---------------- kernel 2: rulebook. meta[p]={selfidx,cnt}; rbent: non-self only --
__global__ __launch_bounds__(256) void k_rulebook(
    const int* __restrict__ cb, const int* __restrict__ cy, const int* __restrict__ cx,
    const int* __restrict__ idx_map, int2* __restrict__ meta, int* __restrict__ rbent, int n)
{
    int i = blockIdx.x * blockDim.x + threadIdx.x;
    if (i >= n) return;
    int b = cb[i], y = cy[i], x = cx[i];
    int s = idx_map[((long)b * CH + y) * CW + x];   // may differ from i on dup coords
    int cnt = 0;
    int base = i * 8;
    #pragma unroll
    for (int k = 0; k < 9; ++k) {
        if (k == 4) continue;
        int dy = k / 3 - 1, dx = k % 3 - 1;
        int ny = y + dy, nx = x + dx;
        if (ny >= 0 && ny < CH && nx >= 0 && nx < CW) {
            int nb = idx_map[((long)b * CH + ny) * CW + nx];
            if (nb >= 0) {
                int kk = (k < 4) ? k : k - 1;       // compacted 0..7 (skip self)
                rbent[base + cnt] = (nb << 3) | kk;
                ++cnt;
            }
        }
    }
    meta[i] = make_int2(s, cnt);
}

// ---------------- kernel 3: sparse conv + fused BN (+identity) + ReLU ---------------
// lane = output channel o; half-wave owns 2 points (4 pts/wave, 16/block-iter).
// Self (k=4) W column held in 32 VGPRs -> dense GEMV, no LDS at all.
// Rare non-self entries read their W row via broadcast global loads (L2-hot, 36KB).
// __launch_bounds__(256,4): allocator may use up to ~128 VGPR so w4[] stays in
// registers (round 3's forced (256,8) spilled it to scratch: 575MB fetch, 4.7x slower).
// Actual VGPR ~64 -> HW still grants 8 waves/SIMD at runtime.
template<bool ADD_ID>
__global__ __launch_bounds__(256, 4) void k_conv(
    const float* __restrict__ in, const float* __restrict__ idn, float* __restrict__ out,
    const float* __restrict__ W,      // [9][32][32] (k,c,o)
    const float* __restrict__ bias,
    const float* __restrict__ gamma, const float* __restrict__ beta,
    const float* __restrict__ mean, const float* __restrict__ var,
    const int2* __restrict__ meta, const int* __restrict__ rbent, int n)
{
    int o = threadIdx.x & 31;

    // self weight column in registers: w4[c] = W[4][c][o]
    float w4[32];
    #pragma unroll
    for (int c = 0; c < 32; ++c) w4[c] = W[4 * 1024 + c * 32 + o];

    int half = (threadIdx.x >> 5) & 1;
    int waveid = threadIdx.x >> 6;
    int unit = waveid * 2 + half;          // 0..7

    float sc = gamma[o] * rsqrtf(var[o] + EPSV);
    float sh = (bias[o] - mean[o]) * sc + beta[o];

    const int PPB = 16;
    for (int p0 = blockIdx.x * PPB; p0 < n; p0 += gridDim.x * PPB) {
        int pA = p0 + unit * 2;
        int pB = pA + 1;
        bool vA = pA < n, vB = pB < n;

        int2 mA = vA ? meta[pA] : make_int2(0, 0);
        int2 mB = vB ? meta[pB] : make_int2(0, 0);

        const float4* xpA = (const float4*)(in + (size_t)mA.x * NC);
        const float4* xpB = (const float4*)(in + (size_t)mB.x * NC);

        float accA = 0.f, accB = 0.f;
        #pragma unroll
        for (int j = 0; j < 8; ++j) {
            float4 a = vA ? xpA[j] : make_float4(0, 0, 0, 0);
            float4 b = vB ? xpB[j] : make_float4(0, 0, 0, 0);
            accA += a.x * w4[4*j] + a.y * w4[4*j+1] + a.z * w4[4*j+2] + a.w * w4[4*j+3];
            accB += b.x * w4[4*j] + b.y * w4[4*j+1] + b.z * w4[4*j+2] + b.w * w4[4*j+3];
        }

        // rare neighbor entries (W rows via broadcast global loads, L2-hot)
        for (int e = 0; e < mA.y; ++e) {
            int en = rbent[pA * 8 + e];
            int kk = en & 7, idx = en >> 3;
            int k = (kk < 4) ? kk : kk + 1;
            const float4* xp = (const float4*)(in + (size_t)idx * NC);
            const float*  wc = W + k * 1024 + o;
            #pragma unroll
            for (int j = 0; j < 8; ++j) {
                float4 xv = xp[j];
                accA += xv.x * wc[(4*j+0)*32] + xv.y * wc[(4*j+1)*32]
                      + xv.z * wc[(4*j+2)*32] + xv.w * wc[(4*j+3)*32];
            }
        }
        for (int e = 0; e < mB.y; ++e) {
            int en = rbent[pB * 8 + e];
            int kk = en & 7, idx = en >> 3;
            int k = (kk < 4) ? kk : kk + 1;
            const float4* xp = (const float4*)(in + (size_t)idx * NC);
            const float*  wc = W + k * 1024 + o;
            #pragma unroll
            for (int j = 0; j < 8; ++j) {
                float4 xv = xp[j];
                accB += xv.x * wc[(4*j+0)*32] + xv.y * wc[(4*j+1)*32]
                      + xv.z * wc[(4*j+2)*32] + xv.w * wc[(4*j+3)*32];
            }
        }

        if (vA) {
            float y = accA * sc + sh;
            if (ADD_ID) y += idn[(size_t)pA * NC + o];
            out[(size_t)pA * NC + o] = fmaxf(y, 0.f);
        }
        if (vB) {
            float y = accB * sc + sh;
            if (ADD_ID) y += idn[(size_t)pB * NC + o];
            out[(size_t)pB * NC + o] = fmaxf(y, 0.f);
        }
    }
}

extern "C" void kernel_launch(void* const* d_in, const int* in_sizes, int n_in,
                              void* d_out, int out_size, void* d_ws, size_t ws_size,
                              hipStream_t stream)
{
    const float* feats = (const float*)d_in[0];
    const float* Wk    = (const float*)d_in[1];  // [3][2][9][32][32]
    const float* bias  = (const float*)d_in[2];
    const float* gamma = (const float*)d_in[3];
    const float* beta  = (const float*)d_in[4];
    const float* mean  = (const float*)d_in[5];
    const float* var   = (const float*)d_in[6];
    const int* cb = (const int*)d_in[7];
    const int* cy = (const int*)d_in[8];
    const int* cx = (const int*)d_in[9];
    float* out = (float*)d_out;
    int n = in_sizes[0] / NC;

    char* ws = (char*)d_ws;
    int*   idx_map = (int*)(ws + 0);                       // 33,177,600 B
    int2*  meta    = (int2*)(ws + 33177600);               // 1,600,000 B
    int*   rbent   = (int*)(ws + 34777600);                // 6,400,000 B
    float* tmp     = (float*)(ws + 41177600);              // 25,600,000 B
    float* hbuf    = (float*)(ws + 66777600);              // 25,600,000 B

    hipMemsetAsync(idx_map, 0xFF, (size_t)CB * CH * CW * sizeof(int), stream);

    int blocks = (n + 255) / 256;
    k_build_map<<<blocks, 256, 0, stream>>>(cb, cy, cx, idx_map, n);
    k_rulebook<<<blocks, 256, 0, stream>>>(cb, cy, cx, idx_map, meta, rbent, n);

    const int CONV_GRID = 2048; // 8 blocks/CU if VGPR<=64 at runtime
    const float* hin = feats;
    for (int i = 0; i < NB_; ++i) {
        int l1 = i * 2 + 0, l2 = i * 2 + 1;
        k_conv<false><<<CONV_GRID, 256, 0, stream>>>(
            hin, nullptr, tmp,
            Wk + (size_t)l1 * 9 * 32 * 32, bias + l1 * 32,
            gamma + l1 * 32, beta + l1 * 32, mean + l1 * 32, var + l1 * 32,
            meta, rbent, n);
        float* outp = (i == NB_ - 1) ? out : hbuf;
        k_conv<true><<<CONV_GRID, 256, 0, stream>>>(
            tmp, hin, outp,
            Wk + (size_t)l2 * 9 * 32 * 32, bias + l2 * 32,
            gamma + l2 * 32, beta + l2 * 32, mean + l2 * 32, var + l2 * 32,
            meta, rbent, n);
        hin = (i == NB_ - 1) ? out : hbuf;
    }
}

// Round 5
// 361.232 us; speedup vs baseline: 3.8651x; 1.0935x over previous
//
#include <hip/hip_runtime.h>

#define NB_ 3
#define CB 4
#define CH 1440
#define CW 1440
#define NC 32
#define EPSV 1e-3f

__device__ __forceinline__ float bfl(unsigned u) { return __uint_as_float(u << 16); }
__device__ __forceinline__ float bfh(unsigned u) { return __uint_as_float(u & 0xffff0000u); }

// ---------------- kernel 1: build idx_map via atomicMax (numpy last-write-wins) ----
__global__ __launch_bounds__(256) void k_build_map(
    const int* __restrict__ cb, const int* __restrict__ cy, const int* __restrict__ cx,
    int* __restrict__ idx_map, int n)
{
    int i = blockIdx.x * blockDim.x + threadIdx.x;
    if (i < n) {
        long cell = ((long)cb[i] * CH + cy[i]) * CW + cx[i];
        atomicMax(&idx_map[cell], i);
    }
}

// ---------------- kernel 2: rulebook. meta[p]={selfidx,cnt}; rbent: non-self only --
__global__ __launch_bounds__(256) void k_rulebook(
    const int* __restrict__ cb, const int* __restrict__ cy, const int* __restrict__ cx,
    const int* __restrict__ idx_map, int2* __restrict__ meta, int* __restrict__ rbent, int n)
{
    int i = blockIdx.x * blockDim.x + threadIdx.x;
    if (i >= n) return;
    int b = cb[i], y = cy[i], x = cx[i];
    int s = idx_map[((long)b * CH + y) * CW + x];   // may differ from i on dup coords
    int cnt = 0;
    int base = i * 8;
    #pragma unroll
    for (int k = 0; k < 9; ++k) {
        if (k == 4) continue;
        int dy = k / 3 - 1, dx = k % 3 - 1;
        int ny = y + dy, nx = x + dx;
        if (ny >= 0 && ny < CH && nx >= 0 && nx < CW) {
            int nb = idx_map[((long)b * CH + ny) * CW + nx];
            if (nb >= 0) {
                int kk = (k < 4) ? k : k - 1;       // compacted 0..7 (skip self)
                rbent[base + cnt] = (nb << 3) | kk;
                ++cnt;
            }
        }
    }
    meta[i] = make_int2(s, cnt);
}

// ---------------- kernel 3: sparse conv + fused BN (+identity) + ReLU ---------------
// lane = output channel o; half-wave owns 2 points (4 pts/wave, 16/block-iter).
// ALL weights (9 offsets) live in LDS as bf16, layout [k][chunk j][o][8 elems]:
//   - 18,432 B -> 8 blocks/CU LDS-wise
//   - per-quarter-wave ds_read_b128 at 16B/lane = 2-way bank alias = free (m136)
//   - no w4[] register array -> VGPR ~48 -> tests the "VGPR=64 caps occupancy
//     at 33%" hypothesis from r2/r4
// x stays f32; accumulate f32; bf16 weight rounding adds <0.02 absmax
// (threshold 0.105, r4 margin 13x).
template<bool ADD_ID>
__global__ __launch_bounds__(256, 4) void k_conv(
    const float* __restrict__ in, const float* __restrict__ idn, float* __restrict__ out,
    const float* __restrict__ W,      // [9][32][32] (k,c,o) f32
    const float* __restrict__ bias,
    const float* __restrict__ gamma, const float* __restrict__ beta,
    const float* __restrict__ mean, const float* __restrict__ var,
    const int2* __restrict__ meta, const int* __restrict__ rbent, int n)
{
    __shared__ uint4 WlQ[9 * 4 * 32];   // 18,432 B; [k][j][o] -> 8 bf16 (c=8j..8j+7)

    int o = threadIdx.x & 31;

    {
        unsigned short* Wl = (unsigned short*)WlQ;
        for (int t = threadIdx.x; t < 9 * 32 * 32; t += 256) {
            int o2 = t & 31, c = (t >> 5) & 31, k = t >> 10;
            unsigned u = __float_as_uint(W[k * 1024 + c * 32 + o2]);
            u += 0x7fffu + ((u >> 16) & 1u);               // RNE to bf16
            Wl[((k * 4 + (c >> 3)) * 32 + o2) * 8 + (c & 7)] = (unsigned short)(u >> 16);
        }
    }
    __syncthreads();

    int half = (threadIdx.x >> 5) & 1;
    int waveid = threadIdx.x >> 6;
    int unit = waveid * 2 + half;          // 0..7

    float sc = gamma[o] * rsqrtf(var[o] + EPSV);
    float sh = (bias[o] - mean[o]) * sc + beta[o];

    const int PPB = 16;
    for (int p0 = blockIdx.x * PPB; p0 < n; p0 += gridDim.x * PPB) {
        int pA = p0 + unit * 2;
        int pB = pA + 1;
        bool vA = pA < n, vB = pB < n;

        int2 mA = vA ? meta[pA] : make_int2(0, 0);
        int2 mB = vB ? meta[pB] : make_int2(0, 0);

        const float4* xpA = (const float4*)(in + (size_t)mA.x * NC);
        const float4* xpB = (const float4*)(in + (size_t)mB.x * NC);

        float accA = 0.f, accB = 0.f;
        #pragma unroll
        for (int j = 0; j < 4; ++j) {
            uint4 wq = WlQ[(16 + j) * 32 + o];             // k=4 (self)
            float4 a0 = vA ? xpA[2*j]   : make_float4(0,0,0,0);
            float4 a1 = vA ? xpA[2*j+1] : make_float4(0,0,0,0);
            float4 b0 = vB ? xpB[2*j]   : make_float4(0,0,0,0);
            float4 b1 = vB ? xpB[2*j+1] : make_float4(0,0,0,0);
            float w0 = bfl(wq.x), w1 = bfh(wq.x), w2 = bfl(wq.y), w3 = bfh(wq.y);
            float w4 = bfl(wq.z), w5 = bfh(wq.z), w6 = bfl(wq.w), w7 = bfh(wq.w);
            accA += a0.x*w0 + a0.y*w1 + a0.z*w2 + a0.w*w3
                  + a1.x*w4 + a1.y*w5 + a1.z*w6 + a1.w*w7;
            accB += b0.x*w0 + b0.y*w1 + b0.z*w2 + b0.w*w3
                  + b1.x*w4 + b1.y*w5 + b1.z*w6 + b1.w*w7;
        }

        // rare non-self entries (weights from LDS, same conflict-free layout)
        for (int e = 0; e < mA.y; ++e) {
            int en = rbent[pA * 8 + e];
            int kk = en & 7, idx = en >> 3;
            int k = (kk < 4) ? kk : kk + 1;
            const float4* xp = (const float4*)(in + (size_t)idx * NC);
            #pragma unroll
            for (int j = 0; j < 4; ++j) {
                uint4 wq = WlQ[(k * 4 + j) * 32 + o];
                float4 x0 = xp[2*j], x1 = xp[2*j+1];
                accA += x0.x*bfl(wq.x) + x0.y*bfh(wq.x) + x0.z*bfl(wq.y) + x0.w*bfh(wq.y)
                      + x1.x*bfl(wq.z) + x1.y*bfh(wq.z) + x1.z*bfl(wq.w) + x1.w*bfh(wq.w);
            }
        }
        for (int e = 0; e < mB.y; ++e) {
            int en = rbent[pB * 8 + e];
            int kk = en & 7, idx = en >> 3;
            int k = (kk < 4) ? kk : kk + 1;
            const float4* xp = (const float4*)(in + (size_t)idx * NC);
            #pragma unroll
            for (int j = 0; j < 4; ++j) {
                uint4 wq = WlQ[(k * 4 + j) * 32 + o];
                float4 x0 = xp[2*j], x1 = xp[2*j+1];
                accB += x0.x*bfl(wq.x) + x0.y*bfh(wq.x) + x0.z*bfl(wq.y) + x0.w*bfh(wq.y)
                      + x1.x*bfl(wq.z) + x1.y*bfh(wq.z) + x1.z*bfl(wq.w) + x1.w*bfh(wq.w);
            }
        }

        if (vA) {
            float y = accA * sc + sh;
            if (ADD_ID) y += idn[(size_t)pA * NC + o];
            out[(size_t)pA * NC + o] = fmaxf(y, 0.f);
        }
        if (vB) {
            float y = accB * sc + sh;
            if (ADD_ID) y += idn[(size_t)pB * NC + o];
            out[(size_t)pB * NC + o] = fmaxf(y, 0.f);
        }
    }
}

extern "C" void kernel_launch(void* const* d_in, const int* in_sizes, int n_in,
                              void* d_out, int out_size, void* d_ws, size_t ws_size,
                              hipStream_t stream)
{
    const float* feats = (const float*)d_in[0];
    const float* Wk    = (const float*)d_in[1];  // [3][2][9][32][32]
    const float* bias  = (const float*)d_in[2];
    const float* gamma = (const float*)d_in[3];
    const float* beta  = (const float*)d_in[4];
    const float* mean  = (const float*)d_in[5];
    const float* var   = (const float*)d_in[6];
    const int* cb = (const int*)d_in[7];
    const int* cy = (const int*)d_in[8];
    const int* cx = (const int*)d_in[9];
    float* out = (float*)d_out;
    int n = in_sizes[0] / NC;

    char* ws = (char*)d_ws;
    int*   idx_map = (int*)(ws + 0);                       // 33,177,600 B
    int2*  meta    = (int2*)(ws + 33177600);               // 1,600,000 B
    int*   rbent   = (int*)(ws + 34777600);                // 6,400,000 B
    float* tmp     = (float*)(ws + 41177600);              // 25,600,000 B
    float* hbuf    = (float*)(ws + 66777600);              // 25,600,000 B

    hipMemsetAsync(idx_map, 0xFF, (size_t)CB * CH * CW * sizeof(int), stream);

    int blocks = (n + 255) / 256;
    k_build_map<<<blocks, 256, 0, stream>>>(cb, cy, cx, idx_map, n);
    k_rulebook<<<blocks, 256, 0, stream>>>(cb, cy, cx, idx_map, meta, rbent, n);

    const int CONV_GRID = 2048; // 8 blocks/CU (LDS 18.4KB, VGPR target ~48)
    const float* hin = feats;
    for (int i = 0; i < NB_; ++i) {
        int l1 = i * 2 + 0, l2 = i * 2 + 1;
        k_conv<false><<<CONV_GRID, 256, 0, stream>>>(
            hin, nullptr, tmp,
            Wk + (size_t)l1 * 9 * 32 * 32, bias + l1 * 32,
            gamma + l1 * 32, beta + l1 * 32, mean + l1 * 32, var + l1 * 32,
            meta, rbent, n);
        float* outp = (i == NB_ - 1) ? out : hbuf;
        k_conv<true><<<CONV_GRID, 256, 0, stream>>>(
            tmp, hin, outp,
            Wk + (size_t)l2 * 9 * 32 * 32, bias + l2 * 32,
            gamma + l2 * 32, beta + l2 * 32, mean + l2 * 32, var + l2 * 32,
            meta, rbent, n);
        hin = (i == NB_ - 1) ? out : hbuf;
    }
}

// Round 6
// 314.841 us; speedup vs baseline: 4.4347x; 1.1474x over previous
//
#include <hip/hip_runtime.h>

#define NB_ 3
#define CB 4
#define CH 1440
#define CW 1440
#define NC 32
#define EPSV 1e-3f
#define PPB 16   // points per block-iteration (x-tile rows)

__device__ __forceinline__ float bfl(unsigned u) { return __uint_as_float(u << 16); }
__device__ __forceinline__ float bfh(unsigned u) { return __uint_as_float(u & 0xffff0000u); }

__device__ __forceinline__ void gload_lds16(const float* g, float* l) {
    __builtin_amdgcn_global_load_lds(
        (const __attribute__((address_space(1))) unsigned int*)g,
        (__attribute__((address_space(3))) unsigned int*)l,
        16, 0, 0);
}

// ---------------- kernel 1: build idx_map via atomicMax (numpy last-write-wins) ----
__global__ __launch_bounds__(256) void k_build_map(
    const int* __restrict__ cb, const int* __restrict__ cy, const int* __restrict__ cx,
    int* __restrict__ idx_map, int n)
{
    int i = blockIdx.x * blockDim.x + threadIdx.x;
    if (i < n) {
        long cell = ((long)cb[i] * CH + cy[i]) * CW + cx[i];
        atomicMax(&idx_map[cell], i);
    }
}

// ---------------- kernel 2: rulebook --------------------------------------------
// cntf[p] = (entry_count<<1) | skip_self_flag.  Entries: (idx<<4)|k, k in 0..8.
// Self tap (k=4): if winner s == p it is NOT an entry (conv fast path uses in[p]);
// if s != p (duplicate coords, ~1%) it IS an entry and flag=1.
__global__ __launch_bounds__(256) void k_rulebook(
    const int* __restrict__ cb, const int* __restrict__ cy, const int* __restrict__ cx,
    const int* __restrict__ idx_map, int* __restrict__ cntf, int* __restrict__ rbent, int n)
{
    int i = blockIdx.x * blockDim.x + threadIdx.x;
    if (i >= n) return;
    int b = cb[i], y = cy[i], x = cx[i];
    int s = idx_map[((long)b * CH + y) * CW + x];
    int cnt = 0;
    int base = i * 9;
    #pragma unroll
    for (int k = 0; k < 9; ++k) {
        if (k == 4) {
            if (s != i) rbent[base + cnt++] = (s << 4) | 4;
            continue;
        }
        int dy = k / 3 - 1, dx = k % 3 - 1;
        int ny = y + dy, nx = x + dx;
        if (ny >= 0 && ny < CH && nx >= 0 && nx < CW) {
            int nb = idx_map[((long)b * CH + ny) * CW + nx];
            if (nb >= 0) rbent[base + cnt++] = (nb << 4) | k;
        }
    }
    cntf[i] = (cnt << 1) | (s != i ? 1 : 0);
}

// ---------------- kernel 3: sparse conv + fused BN (+identity) + ReLU ---------------
// unit = 32 lanes handles 2 points; lane = output channel o.
// Self rows arrive via LDS double-buffer staged with global_load_lds one iteration
// ahead (latency hidden under compute; compiler drains vmcnt at the barrier).
// Weights: all 9 offsets in LDS as bf16 [k][j][o][8].
template<bool ADD_ID>
__global__ __launch_bounds__(256, 4) void k_conv(
    const float* __restrict__ in, const float* __restrict__ idn, float* __restrict__ out,
    const float* __restrict__ W,      // [9][32][32] (k,c,o) f32
    const float* __restrict__ bias,
    const float* __restrict__ gamma, const float* __restrict__ beta,
    const float* __restrict__ mean, const float* __restrict__ var,
    const int* __restrict__ cntf, const int* __restrict__ rbent, int n)
{
    __shared__ uint4 WlQ[9 * 4 * 32];      // 18,432 B
    __shared__ float xt[2][PPB * NC];      // 2 x 2,048 B

    int o = threadIdx.x & 31;
    int unit = threadIdx.x >> 5;           // 0..7

    {
        unsigned short* Wl = (unsigned short*)WlQ;
        for (int t = threadIdx.x; t < 9 * 32 * 32; t += 256) {
            int o2 = t & 31, c = (t >> 5) & 31, k = t >> 10;
            unsigned u = __float_as_uint(W[k * 1024 + c * 32 + o2]);
            u += 0x7fffu + ((u >> 16) & 1u);               // RNE to bf16
            Wl[((k * 4 + (c >> 3)) * 32 + o2) * 8 + (c & 7)] = (unsigned short)(u >> 16);
        }
    }

    float sc = gamma[o] * rsqrtf(var[o] + EPSV);
    float sh = (bias[o] - mean[o]) * sc + beta[o];

    int start = blockIdx.x * PPB;
    const int stride = gridDim.x * PPB;

    // prologue stage: tile for first iteration into buf 0
    if (start < n && threadIdx.x < PPB * NC / 4) {
        int t = threadIdx.x;
        int p = start + (t >> 3); if (p >= n) p = n - 1;
        gload_lds16(in + (size_t)p * NC + (t & 7) * 4, &xt[0][t * 4]);
    }

    int cur = 0;
    for (int p0 = start; p0 < n; p0 += stride) {
        __syncthreads();   // drains vmcnt: current tile ready; also W ready on iter 0

        int p0n = p0 + stride;
        if (p0n < n && threadIdx.x < PPB * NC / 4) {
            int t = threadIdx.x;
            int p = p0n + (t >> 3); if (p >= n) p = n - 1;
            gload_lds16(in + (size_t)p * NC + (t & 7) * 4, &xt[cur ^ 1][t * 4]);
        }

        int pA = p0 + unit * 2;
        int pB = pA + 1;
        bool vA = pA < n, vB = pB < n;

        int rbA = (vA ? pA : n - 1) * 9;
        int rbB = (vB ? pB : n - 1) * 9;
        int cfA = vA ? cntf[pA] : 0;
        int cfB = vB ? cntf[pB] : 0;
        int eA0 = rbent[rbA];              // speculative first entry
        int eB0 = rbent[rbB];

        const float4* xA4 = (const float4*)(xt[cur] + (unit * 2 + 0) * NC);
        const float4* xB4 = (const float4*)(xt[cur] + (unit * 2 + 1) * NC);

        float accA = 0.f, accB = 0.f;
        #pragma unroll
        for (int j = 0; j < 4; ++j) {
            uint4 wq = WlQ[(16 + j) * 32 + o];             // k=4 (self)
            float4 a0 = xA4[2 * j], a1 = xA4[2 * j + 1];
            float4 b0 = xB4[2 * j], b1 = xB4[2 * j + 1];
            float w0 = bfl(wq.x), w1 = bfh(wq.x), w2 = bfl(wq.y), w3 = bfh(wq.y);
            float w4 = bfl(wq.z), w5 = bfh(wq.z), w6 = bfl(wq.w), w7 = bfh(wq.w);
            accA += a0.x*w0 + a0.y*w1 + a0.z*w2 + a0.w*w3
                  + a1.x*w4 + a1.y*w5 + a1.z*w6 + a1.w*w7;
            accB += b0.x*w0 + b0.y*w1 + b0.z*w2 + b0.w*w3
                  + b1.x*w4 + b1.y*w5 + b1.z*w6 + b1.w*w7;
        }
        if (cfA & 1) accA = 0.f;           // dup-self: tap comes via rulebook
        if (cfB & 1) accB = 0.f;

        int ecA = cfA >> 1;
        for (int e = 0; e < ecA; ++e) {
            int en = (e == 0) ? eA0 : rbent[rbA + e];
            int k = en & 15, idx = en >> 4;
            const float4* xp = (const float4*)(in + (size_t)idx * NC);
            #pragma unroll
            for (int j = 0; j < 4; ++j) {
                uint4 wq = WlQ[(k * 4 + j) * 32 + o];
                float4 x0 = xp[2 * j], x1 = xp[2 * j + 1];
                accA += x0.x*bfl(wq.x) + x0.y*bfh(wq.x) + x0.z*bfl(wq.y) + x0.w*bfh(wq.y)
                      + x1.x*bfl(wq.z) + x1.y*bfh(wq.z) + x1.z*bfl(wq.w) + x1.w*bfh(wq.w);
            }
        }
        int ecB = cfB >> 1;
        for (int e = 0; e < ecB; ++e) {
            int en = (e == 0) ? eB0 : rbent[rbB + e];
            int k = en & 15, idx = en >> 4;
            const float4* xp = (const float4*)(in + (size_t)idx * NC);
            #pragma unroll
            for (int j = 0; j < 4; ++j) {
                uint4 wq = WlQ[(k * 4 + j) * 32 + o];
                float4 x0 = xp[2 * j], x1 = xp[2 * j + 1];
                accB += x0.x*bfl(wq.x) + x0.y*bfh(wq.x) + x0.z*bfl(wq.y) + x0.w*bfh(wq.y)
                      + x1.x*bfl(wq.z) + x1.y*bfh(wq.z) + x1.z*bfl(wq.w) + x1.w*bfh(wq.w);
            }
        }

        if (vA) {
            float y = accA * sc + sh;
            if (ADD_ID) y += idn[(size_t)pA * NC + o];
            out[(size_t)pA * NC + o] = fmaxf(y, 0.f);
        }
        if (vB) {
            float y = accB * sc + sh;
            if (ADD_ID) y += idn[(size_t)pB * NC + o];
            out[(size_t)pB * NC + o] = fmaxf(y, 0.f);
        }
        cur ^= 1;
    }
}

extern "C" void kernel_launch(void* const* d_in, const int* in_sizes, int n_in,
                              void* d_out, int out_size, void* d_ws, size_t ws_size,
                              hipStream_t stream)
{
    const float* feats = (const float*)d_in[0];
    const float* Wk    = (const float*)d_in[1];  // [3][2][9][32][32]
    const float* bias  = (const float*)d_in[2];
    const float* gamma = (const float*)d_in[3];
    const float* beta  = (const float*)d_in[4];
    const float* mean  = (const float*)d_in[5];
    const float* var   = (const float*)d_in[6];
    const int* cb = (const int*)d_in[7];
    const int* cy = (const int*)d_in[8];
    const int* cx = (const int*)d_in[9];
    float* out = (float*)d_out;
    int n = in_sizes[0] / NC;

    char* ws = (char*)d_ws;
    int*   idx_map = (int*)(ws + 0);                       // 33,177,600 B
    int*   cntf    = (int*)(ws + 33177600);                //    800,000 B
    int*   rbent   = (int*)(ws + 33977600);                //  7,200,000 B
    float* tmp     = (float*)(ws + 41177600);              // 25,600,000 B
    float* hbuf    = (float*)(ws + 66777600);              // 25,600,000 B

    hipMemsetAsync(idx_map, 0xFF, (size_t)CB * CH * CW * sizeof(int), stream);

    int blocks = (n + 255) / 256;
    k_build_map<<<blocks, 256, 0, stream>>>(cb, cy, cx, idx_map, n);
    k_rulebook<<<blocks, 256, 0, stream>>>(cb, cy, cx, idx_map, cntf, rbent, n);

    const int CONV_GRID = 1792; // 7 blocks/CU (LDS 22.5 KB)
    const float* hin = feats;
    for (int i = 0; i < NB_; ++i) {
        int l1 = i * 2 + 0, l2 = i * 2 + 1;
        k_conv<false><<<CONV_GRID, 256, 0, stream>>>(
            hin, nullptr, tmp,
            Wk + (size_t)l1 * 9 * 32 * 32, bias + l1 * 32,
            gamma + l1 * 32, beta + l1 * 32, mean + l1 * 32, var + l1 * 32,
            cntf, rbent, n);
        float* outp = (i == NB_ - 1) ? out : hbuf;
        k_conv<true><<<CONV_GRID, 256, 0, stream>>>(
            tmp, hin, outp,
            Wk + (size_t)l2 * 9 * 32 * 32, bias + l2 * 32,
            gamma + l2 * 32, beta + l2 * 32, mean + l2 * 32, var + l2 * 32,
            cntf, rbent, n);
        hin = (i == NB_ - 1) ? out : hbuf;
    }
}

// Round 7
// 181.136 us; speedup vs baseline: 7.7081x; 1.7381x over previous
//
#include <hip/hip_runtime.h>

#define NB_ 3
#define CB 4
#define CH 1440
#define CW 1440
#define NC 32
#define EPSV 1e-3f

typedef __attribute__((ext_vector_type(8))) short bf16x8;
typedef __attribute__((ext_vector_type(4))) float f32x4;

union U16 { uint4 u; bf16x8 v; };

__device__ __forceinline__ unsigned pk2(float a, float b) {
    unsigned ua = __float_as_uint(a), ub = __float_as_uint(b);
    ua += 0x7fffu + ((ua >> 16) & 1u);
    ub += 0x7fffu + ((ub >> 16) & 1u);
    return (ua >> 16) | (ub & 0xffff0000u);
}
__device__ __forceinline__ unsigned short f2b(float a) {
    unsigned u = __float_as_uint(a);
    u += 0x7fffu + ((u >> 16) & 1u);
    return (unsigned short)(u >> 16);
}
__device__ __forceinline__ float b2f(unsigned short s) {
    return __uint_as_float(((unsigned)s) << 16);
}

// ---------------- kernel 1: build idx_map via atomicMax (numpy last-write-wins) ----
__global__ __launch_bounds__(256) void k_build_map(
    const int* __restrict__ cb, const int* __restrict__ cy, const int* __restrict__ cx,
    int* __restrict__ idx_map, int n)
{
    int i = blockIdx.x * blockDim.x + threadIdx.x;
    if (i < n) {
        long cell = ((long)cb[i] * CH + cy[i]) * CW + cx[i];
        atomicMax(&idx_map[cell], i);
    }
}

// ---------------- kernel 2: dense rulebook nidx[9][n] + per-16pt-tile k-mask -------
__global__ __launch_bounds__(256) void k_rulebook(
    const int* __restrict__ cb, const int* __restrict__ cy, const int* __restrict__ cx,
    const int* __restrict__ idx_map, int* __restrict__ nidx,
    unsigned* __restrict__ tmask, int n)
{
    int i = blockIdx.x * blockDim.x + threadIdx.x;
    if (i >= n) return;
    int b = cb[i], y = cy[i], x = cx[i];
    unsigned m = 1u << 4;
    nidx[4 * n + i] = idx_map[((long)b * CH + y) * CW + x];   // self winner, always >=0
    #pragma unroll
    for (int k = 0; k < 9; ++k) {
        if (k == 4) continue;
        int dy = k / 3 - 1, dx = k % 3 - 1;
        int ny = y + dy, nx = x + dx;
        int nb = -1;
        if (ny >= 0 && ny < CH && nx >= 0 && nx < CW)
            nb = idx_map[((long)b * CH + ny) * CW + nx];
        nidx[k * n + i] = nb;
        if (nb >= 0) m |= 1u << k;
    }
    atomicOr(&tmask[i >> 4], m);
}

// ---------------- kernel 3: feats f32 -> bf16 --------------------------------------
__global__ __launch_bounds__(256) void k_cvt(
    const float* __restrict__ f, unsigned short* __restrict__ b, int n32)
{
    int i = (blockIdx.x * 256 + threadIdx.x) * 8;
    if (i + 8 <= n32) {
        float4 a0 = *(const float4*)(f + i);
        float4 a1 = *(const float4*)(f + i + 4);
        uint4 r;
        r.x = pk2(a0.x, a0.y); r.y = pk2(a0.z, a0.w);
        r.z = pk2(a1.x, a1.y); r.w = pk2(a1.z, a1.w);
        *(uint4*)(b + i) = r;
    }
}

// ---------------- kernel 4: gather-K MFMA conv + BN (+identity) + ReLU -------------
// One wave = one 16-point tile. A = gathered 16x32 bf16 x-rows (lane: row l&15,
// chans 8*(l>>4)..+8 = one dwordx4). B = W_k B-fragments preconverted in LDS
// ([k][ntile][lane] uint4, 18.4KB). D: row=(l>>4)*4+r, col=l&15 (m89-verified).
// Per-tile k-mask skips offsets with no entries (avg ~3.6 of 9 K-steps).
template<bool ADD_ID, bool F32OUT>
__global__ __launch_bounds__(256, 4) void k_conv(
    const unsigned short* __restrict__ in,   // bf16 [n][32]
    const unsigned short* __restrict__ idn,  // bf16 [n][32]
    void* __restrict__ outv,                 // bf16 or f32 [n][32]
    const float* __restrict__ W,             // [9][32][32] (k,c,o) f32
    const float* __restrict__ bias,
    const float* __restrict__ gamma, const float* __restrict__ beta,
    const float* __restrict__ mean, const float* __restrict__ var,
    const int* __restrict__ nidx, const unsigned* __restrict__ tmask, int n)
{
    __shared__ uint4 Bf[9 * 2 * 64];   // 18,432 B

    int tid = threadIdx.x;
    int l = tid & 63, wv = tid >> 6;

    for (int t = tid; t < 9 * 2 * 64; t += 256) {
        int lane = t & 63, nt = (t >> 6) & 1, k = t >> 7;
        int o = nt * 16 + (lane & 15);
        int c0 = (lane >> 4) * 8;
        const float* wp = W + k * 1024 + o;
        uint4 r;
        r.x = pk2(wp[(c0 + 0) * 32], wp[(c0 + 1) * 32]);
        r.y = pk2(wp[(c0 + 2) * 32], wp[(c0 + 3) * 32]);
        r.z = pk2(wp[(c0 + 4) * 32], wp[(c0 + 5) * 32]);
        r.w = pk2(wp[(c0 + 6) * 32], wp[(c0 + 7) * 32]);
        Bf[t] = r;
    }
    __syncthreads();

    int row = l & 15, grp = l >> 4;
    int o0 = row, o1 = row + 16;

    float sc0 = gamma[o0] * rsqrtf(var[o0] + EPSV);
    float sh0 = (bias[o0] - mean[o0]) * sc0 + beta[o0];
    float sc1 = gamma[o1] * rsqrtf(var[o1] + EPSV);
    float sh1 = (bias[o1] - mean[o1]) * sc1 + beta[o1];

    int ntile = (n + 15) >> 4;
    for (int tile = blockIdx.x * 4 + wv; tile < ntile; tile += gridDim.x * 4) {
        int p0 = tile << 4;
        int pr = p0 + row;
        int prc = min(pr, n - 1);

        f32x4 acc0 = {0.f, 0.f, 0.f, 0.f};
        f32x4 acc1 = {0.f, 0.f, 0.f, 0.f};

        unsigned m = tmask[tile];          // wave-uniform
        while (m) {
            int k = __ffs(m) - 1; m &= m - 1;
            int idx = nidx[k * n + prc];
            bool valid = (idx >= 0) && (pr < n);
            int si = valid ? idx : 0;
            uint4 araw = *(const uint4*)(in + (size_t)si * 32 + grp * 8);
            U16 a;
            a.u.x = valid ? araw.x : 0u;
            a.u.y = valid ? araw.y : 0u;
            a.u.z = valid ? araw.z : 0u;
            a.u.w = valid ? araw.w : 0u;
            U16 b0, b1;
            b0.u = Bf[(k * 2 + 0) * 64 + l];
            b1.u = Bf[(k * 2 + 1) * 64 + l];
            acc0 = __builtin_amdgcn_mfma_f32_16x16x32_bf16(a.v, b0.v, acc0, 0, 0, 0);
            acc1 = __builtin_amdgcn_mfma_f32_16x16x32_bf16(a.v, b1.v, acc1, 0, 0, 0);
        }

        #pragma unroll
        for (int r = 0; r < 4; ++r) {
            int p = p0 + grp * 4 + r;
            if (p < n) {
                float y0 = acc0[r] * sc0 + sh0;
                float y1 = acc1[r] * sc1 + sh1;
                if (ADD_ID) {
                    y0 += b2f(idn[(size_t)p * 32 + o0]);
                    y1 += b2f(idn[(size_t)p * 32 + o1]);
                }
                y0 = fmaxf(y0, 0.f);
                y1 = fmaxf(y1, 0.f);
                if (F32OUT) {
                    ((float*)outv)[(size_t)p * 32 + o0] = y0;
                    ((float*)outv)[(size_t)p * 32 + o1] = y1;
                } else {
                    ((unsigned short*)outv)[(size_t)p * 32 + o0] = f2b(y0);
                    ((unsigned short*)outv)[(size_t)p * 32 + o1] = f2b(y1);
                }
            }
        }
    }
}

extern "C" void kernel_launch(void* const* d_in, const int* in_sizes, int n_in,
                              void* d_out, int out_size, void* d_ws, size_t ws_size,
                              hipStream_t stream)
{
    const float* feats = (const float*)d_in[0];
    const float* Wk    = (const float*)d_in[1];  // [3][2][9][32][32]
    const float* bias  = (const float*)d_in[2];
    const float* gamma = (const float*)d_in[3];
    const float* beta  = (const float*)d_in[4];
    const float* mean  = (const float*)d_in[5];
    const float* var   = (const float*)d_in[6];
    const int* cb = (const int*)d_in[7];
    const int* cy = (const int*)d_in[8];
    const int* cx = (const int*)d_in[9];
    float* out = (float*)d_out;
    int n = in_sizes[0] / NC;

    char* ws = (char*)d_ws;
    int*            idx_map = (int*)(ws + 0);                   // 33,177,600 B
    int*            nidx    = (int*)(ws + 33177600);            //  7,200,000 B
    unsigned*       tmask   = (unsigned*)(ws + 40377600);       //     64,000 B
    unsigned short* xbf     = (unsigned short*)(ws + 40441600); // 12,800,000 B
    unsigned short* tmpbf   = (unsigned short*)(ws + 53241600); // 12,800,000 B
    unsigned short* hb      = (unsigned short*)(ws + 66041600); // 12,800,000 B

    hipMemsetAsync(idx_map, 0xFF, (size_t)CB * CH * CW * sizeof(int), stream);
    hipMemsetAsync(tmask, 0, 64000, stream);

    int blocks = (n + 255) / 256;
    k_build_map<<<blocks, 256, 0, stream>>>(cb, cy, cx, idx_map, n);
    k_rulebook<<<blocks, 256, 0, stream>>>(cb, cy, cx, idx_map, nidx, tmask, n);
    k_cvt<<<(n * NC / 8 + 255) / 256, 256, 0, stream>>>(feats, xbf, n * NC);

    const int G = 1024;  // 4 blocks/CU
    const int WSZ = 9 * 32 * 32; // 9216 floats per layer

    k_conv<false, false><<<G, 256, 0, stream>>>(xbf, nullptr, tmpbf,
        Wk + 0 * WSZ, bias + 0,  gamma + 0,  beta + 0,  mean + 0,  var + 0,  nidx, tmask, n);
    k_conv<true,  false><<<G, 256, 0, stream>>>(tmpbf, xbf, hb,
        Wk + 1 * WSZ, bias + 32, gamma + 32, beta + 32, mean + 32, var + 32, nidx, tmask, n);
    k_conv<false, false><<<G, 256, 0, stream>>>(hb, nullptr, tmpbf,
        Wk + 2 * WSZ, bias + 64, gamma + 64, beta + 64, mean + 64, var + 64, nidx, tmask, n);
    k_conv<true,  false><<<G, 256, 0, stream>>>(tmpbf, hb, xbf,
        Wk + 3 * WSZ, bias + 96, gamma + 96, beta + 96, mean + 96, var + 96, nidx, tmask, n);
    k_conv<false, false><<<G, 256, 0, stream>>>(xbf, nullptr, tmpbf,
        Wk + 4 * WSZ, bias + 128, gamma + 128, beta + 128, mean + 128, var + 128, nidx, tmask, n);
    k_conv<true,  true><<<G, 256, 0, stream>>>(tmpbf, xbf, out,
        Wk + 5 * WSZ, bias + 160, gamma + 160, beta + 160, mean + 160, var + 160, nidx, tmask, n);
}

// Round 8
// 149.503 us; speedup vs baseline: 9.3391x; 1.2116x over previous
//
#include <hip/hip_runtime.h>

#define NB_ 3
#define CB 4
#define CH 1440
#define CW 1440
#define NC 32
#define EPSV 1e-3f

typedef __attribute__((ext_vector_type(8))) short bf16x8;
typedef __attribute__((ext_vector_type(4))) float f32x4;

union U16 { uint4 u; bf16x8 v; };

__device__ __forceinline__ unsigned pk2(float a, float b) {
    unsigned ua = __float_as_uint(a), ub = __float_as_uint(b);
    ua += 0x7fffu + ((ua >> 16) & 1u);
    ub += 0x7fffu + ((ub >> 16) & 1u);
    return (ua >> 16) | (ub & 0xffff0000u);
}
__device__ __forceinline__ unsigned short f2b(float a) {
    unsigned u = __float_as_uint(a);
    u += 0x7fffu + ((u >> 16) & 1u);
    return (unsigned short)(u >> 16);
}
__device__ __forceinline__ float b2f(unsigned short s) {
    return __uint_as_float(((unsigned)s) << 16);
}

// ---------------- kernel 0: scatter-clear the 3x3 neighborhood of every point ------
// Replaces the 33MB memset (40us/replay). Every cell the rulebook will read lies in
// some point's neighborhood, so clearing those suffices; deterministic per replay.
__global__ __launch_bounds__(256) void k_clear(
    const int* __restrict__ cb, const int* __restrict__ cy, const int* __restrict__ cx,
    int* __restrict__ idx_map, int n)
{
    int i = blockIdx.x * blockDim.x + threadIdx.x;
    if (i >= n) return;
    int b = cb[i], y = cy[i], x = cx[i];
    #pragma unroll
    for (int dy = -1; dy <= 1; ++dy) {
        int yy = y + dy;
        if (yy < 0 || yy >= CH) continue;
        #pragma unroll
        for (int dx = -1; dx <= 1; ++dx) {
            int xx = x + dx;
            if (xx < 0 || xx >= CW) continue;
            idx_map[((long)b * CH + yy) * CW + xx] = -1;
        }
    }
}

// ---------------- kernel 1: build idx_map via atomicMax (numpy last-write-wins) ----
__global__ __launch_bounds__(256) void k_build_map(
    const int* __restrict__ cb, const int* __restrict__ cy, const int* __restrict__ cx,
    int* __restrict__ idx_map, int n)
{
    int i = blockIdx.x * blockDim.x + threadIdx.x;
    if (i < n) {
        long cell = ((long)cb[i] * CH + cy[i]) * CW + cx[i];
        atomicMax(&idx_map[cell], i);
    }
}

// ---------------- kernel 2: dense rulebook nidx[9][n] ------------------------------
__global__ __launch_bounds__(256) void k_rulebook(
    const int* __restrict__ cb, const int* __restrict__ cy, const int* __restrict__ cx,
    const int* __restrict__ idx_map, int* __restrict__ nidx, int n)
{
    int i = blockIdx.x * blockDim.x + threadIdx.x;
    if (i >= n) return;
    int b = cb[i], y = cy[i], x = cx[i];
    nidx[4 * n + i] = idx_map[((long)b * CH + y) * CW + x];   // self winner, >=0
    #pragma unroll
    for (int k = 0; k < 9; ++k) {
        if (k == 4) continue;
        int dy = k / 3 - 1, dx = k % 3 - 1;
        int ny = y + dy, nx = x + dx;
        int nb = -1;
        if (ny >= 0 && ny < CH && nx >= 0 && nx < CW)
            nb = idx_map[((long)b * CH + ny) * CW + nx];
        nidx[k * n + i] = nb;
    }
}

// ---------------- kernel 3: feats f32 -> bf16 --------------------------------------
__global__ __launch_bounds__(256) void k_cvt(
    const float* __restrict__ f, unsigned short* __restrict__ b, int n32)
{
    int i = (blockIdx.x * 256 + threadIdx.x) * 8;
    if (i + 8 <= n32) {
        float4 a0 = *(const float4*)(f + i);
        float4 a1 = *(const float4*)(f + i + 4);
        uint4 r;
        r.x = pk2(a0.x, a0.y); r.y = pk2(a0.z, a0.w);
        r.z = pk2(a1.x, a1.y); r.w = pk2(a1.z, a1.w);
        *(uint4*)(b + i) = r;
    }
}

// ---------------- kernel 4: gather-K MFMA conv + BN (+identity) + ReLU -------------
// One wave = one 16-point tile. Flattened dependence chain:
//   (1) all 9 nidx row-indices loaded in parallel (one round-trip)
//   (2) active-k set via __any (replaces tmask; wave-uniform)
//   (3) all active gathers issued in parallel (second round-trip)
//   (4) ~2*3.6 MFMAs back-to-back
// A: lane holds row l&15, chans 8*(l>>4)..+8 (one dwordx4). B: W_k frags in LDS.
// D: row=(l>>4)*4+r, col=l&15 (m89-verified).
template<bool ADD_ID, bool F32OUT>
__global__ __launch_bounds__(256, 4) void k_conv(
    const unsigned short* __restrict__ in,   // bf16 [n][32]
    const unsigned short* __restrict__ idn,  // bf16 [n][32]
    void* __restrict__ outv,                 // bf16 or f32 [n][32]
    const float* __restrict__ W,             // [9][32][32] (k,c,o) f32
    const float* __restrict__ bias,
    const float* __restrict__ gamma, const float* __restrict__ beta,
    const float* __restrict__ mean, const float* __restrict__ var,
    const int* __restrict__ nidx, int n)
{
    __shared__ uint4 Bf[9 * 2 * 64];   // 18,432 B

    int tid = threadIdx.x;
    int l = tid & 63, wv = tid >> 6;

    for (int t = tid; t < 9 * 2 * 64; t += 256) {
        int lane = t & 63, nt = (t >> 6) & 1, k = t >> 7;
        int o = nt * 16 + (lane & 15);
        int c0 = (lane >> 4) * 8;
        const float* wp = W + k * 1024 + o;
        uint4 r;
        r.x = pk2(wp[(c0 + 0) * 32], wp[(c0 + 1) * 32]);
        r.y = pk2(wp[(c0 + 2) * 32], wp[(c0 + 3) * 32]);
        r.z = pk2(wp[(c0 + 4) * 32], wp[(c0 + 5) * 32]);
        r.w = pk2(wp[(c0 + 6) * 32], wp[(c0 + 7) * 32]);
        Bf[t] = r;
    }
    __syncthreads();

    int row = l & 15, grp = l >> 4;
    int o0 = row, o1 = row + 16;

    float sc0 = gamma[o0] * rsqrtf(var[o0] + EPSV);
    float sh0 = (bias[o0] - mean[o0]) * sc0 + beta[o0];
    float sc1 = gamma[o1] * rsqrtf(var[o1] + EPSV);
    float sh1 = (bias[o1] - mean[o1]) * sc1 + beta[o1];

    int ntile = (n + 15) >> 4;
    for (int tile = blockIdx.x * 4 + wv; tile < ntile; tile += gridDim.x * 4) {
        int p0 = tile << 4;
        int pr = p0 + row;
        bool rowok = pr < n;
        int prc = rowok ? pr : n - 1;

        // (1) all 9 neighbor indices in parallel
        int idxk[9];
        #pragma unroll
        for (int k = 0; k < 9; ++k) idxk[k] = nidx[(size_t)k * n + prc];

        // (2)+(3) active set + parallel gathers
        bool act[9];
        U16 a[9];
        #pragma unroll
        for (int k = 0; k < 9; ++k) {
            act[k] = __any(idxk[k] >= 0);
            if (act[k]) {
                bool valid = rowok && (idxk[k] >= 0);
                int si = valid ? idxk[k] : 0;
                uint4 r = *(const uint4*)(in + (size_t)si * 32 + grp * 8);
                a[k].u.x = valid ? r.x : 0u;
                a[k].u.y = valid ? r.y : 0u;
                a[k].u.z = valid ? r.z : 0u;
                a[k].u.w = valid ? r.w : 0u;
            }
        }

        // (4) MFMA chain
        f32x4 acc0 = {0.f, 0.f, 0.f, 0.f};
        f32x4 acc1 = {0.f, 0.f, 0.f, 0.f};
        #pragma unroll
        for (int k = 0; k < 9; ++k) {
            if (act[k]) {
                U16 b0, b1;
                b0.u = Bf[(k * 2 + 0) * 64 + l];
                b1.u = Bf[(k * 2 + 1) * 64 + l];
                acc0 = __builtin_amdgcn_mfma_f32_16x16x32_bf16(a[k].v, b0.v, acc0, 0, 0, 0);
                acc1 = __builtin_amdgcn_mfma_f32_16x16x32_bf16(a[k].v, b1.v, acc1, 0, 0, 0);
            }
        }

        #pragma unroll
        for (int r = 0; r < 4; ++r) {
            int p = p0 + grp * 4 + r;
            if (p < n) {
                float y0 = acc0[r] * sc0 + sh0;
                float y1 = acc1[r] * sc1 + sh1;
                if (ADD_ID) {
                    y0 += b2f(idn[(size_t)p * 32 + o0]);
                    y1 += b2f(idn[(size_t)p * 32 + o1]);
                }
                y0 = fmaxf(y0, 0.f);
                y1 = fmaxf(y1, 0.f);
                if (F32OUT) {
                    ((float*)outv)[(size_t)p * 32 + o0] = y0;
                    ((float*)outv)[(size_t)p * 32 + o1] = y1;
                } else {
                    ((unsigned short*)outv)[(size_t)p * 32 + o0] = f2b(y0);
                    ((unsigned short*)outv)[(size_t)p * 32 + o1] = f2b(y1);
                }
            }
        }
    }
}

extern "C" void kernel_launch(void* const* d_in, const int* in_sizes, int n_in,
                              void* d_out, int out_size, void* d_ws, size_t ws_size,
                              hipStream_t stream)
{
    const float* feats = (const float*)d_in[0];
    const float* Wk    = (const float*)d_in[1];  // [3][2][9][32][32]
    const float* bias  = (const float*)d_in[2];
    const float* gamma = (const float*)d_in[3];
    const float* beta  = (const float*)d_in[4];
    const float* mean  = (const float*)d_in[5];
    const float* var   = (const float*)d_in[6];
    const int* cb = (const int*)d_in[7];
    const int* cy = (const int*)d_in[8];
    const int* cx = (const int*)d_in[9];
    float* out = (float*)d_out;
    int n = in_sizes[0] / NC;

    char* ws = (char*)d_ws;
    int*            idx_map = (int*)(ws + 0);                   // 33,177,600 B
    int*            nidx    = (int*)(ws + 33177600);            //  7,200,000 B
    unsigned short* xbf     = (unsigned short*)(ws + 40441600); // 12,800,000 B
    unsigned short* tmpbf   = (unsigned short*)(ws + 53241600); // 12,800,000 B
    unsigned short* hb      = (unsigned short*)(ws + 66041600); // 12,800,000 B

    int blocks = (n + 255) / 256;
    k_clear<<<blocks, 256, 0, stream>>>(cb, cy, cx, idx_map, n);
    k_build_map<<<blocks, 256, 0, stream>>>(cb, cy, cx, idx_map, n);
    k_rulebook<<<blocks, 256, 0, stream>>>(cb, cy, cx, idx_map, nidx, n);
    k_cvt<<<(n * NC / 8 + 255) / 256, 256, 0, stream>>>(feats, xbf, n * NC);

    const int G = 1024;  // 4 blocks/CU
    const int WSZ = 9 * 32 * 32; // 9216 floats per layer

    k_conv<false, false><<<G, 256, 0, stream>>>(xbf, nullptr, tmpbf,
        Wk + 0 * WSZ, bias + 0,  gamma + 0,  beta + 0,  mean + 0,  var + 0,  nidx, n);
    k_conv<true,  false><<<G, 256, 0, stream>>>(tmpbf, xbf, hb,
        Wk + 1 * WSZ, bias + 32, gamma + 32, beta + 32, mean + 32, var + 32, nidx, n);
    k_conv<false, false><<<G, 256, 0, stream>>>(hb, nullptr, tmpbf,
        Wk + 2 * WSZ, bias + 64, gamma + 64, beta + 64, mean + 64, var + 64, nidx, n);
    k_conv<true,  false><<<G, 256, 0, stream>>>(tmpbf, hb, xbf,
        Wk + 3 * WSZ, bias + 96, gamma + 96, beta + 96, mean + 96, var + 96, nidx, n);
    k_conv<false, false><<<G, 256, 0, stream>>>(xbf, nullptr, tmpbf,
        Wk + 4 * WSZ, bias + 128, gamma + 128, beta + 128, mean + 128, var + 128, nidx, n);
    k_conv<true,  true><<<G, 256, 0, stream>>>(tmpbf, xbf, out,
        Wk + 5 * WSZ, bias + 160, gamma + 160, beta + 160, mean + 160, var + 160, nidx, n);
}

// Round 9
// 148.639 us; speedup vs baseline: 9.3933x; 1.0058x over previous
//
#include <hip/hip_runtime.h>

#define NB_ 3
#define CB 4
#define CH 1440
#define CW 1440
#define NC 32
#define EPSV 1e-3f

typedef __attribute__((ext_vector_type(8))) short bf16x8;
typedef __attribute__((ext_vector_type(16))) float f32x16;

union U16 { uint4 u; bf16x8 v; };

__device__ __forceinline__ unsigned pk2(float a, float b) {
    unsigned ua = __float_as_uint(a), ub = __float_as_uint(b);
    ua += 0x7fffu + ((ua >> 16) & 1u);
    ub += 0x7fffu + ((ub >> 16) & 1u);
    return (ua >> 16) | (ub & 0xffff0000u);
}
__device__ __forceinline__ unsigned short f2b(float a) {
    unsigned u = __float_as_uint(a);
    u += 0x7fffu + ((u >> 16) & 1u);
    return (unsigned short)(u >> 16);
}
__device__ __forceinline__ float b2f(unsigned short s) {
    return __uint_as_float(((unsigned)s) << 16);
}

// ---------------- kernel 0: scatter-clear the 3x3 neighborhood of every point ------
__global__ __launch_bounds__(256) void k_clear(
    const int* __restrict__ cb, const int* __restrict__ cy, const int* __restrict__ cx,
    int* __restrict__ idx_map, int n)
{
    int i = blockIdx.x * blockDim.x + threadIdx.x;
    if (i >= n) return;
    int b = cb[i], y = cy[i], x = cx[i];
    #pragma unroll
    for (int dy = -1; dy <= 1; ++dy) {
        int yy = y + dy;
        if (yy < 0 || yy >= CH) continue;
        #pragma unroll
        for (int dx = -1; dx <= 1; ++dx) {
            int xx = x + dx;
            if (xx < 0 || xx >= CW) continue;
            idx_map[((long)b * CH + yy) * CW + xx] = -1;
        }
    }
}

// ---------------- kernel 1: build idx_map via atomicMax (numpy last-write-wins) ----
__global__ __launch_bounds__(256) void k_build_map(
    const int* __restrict__ cb, const int* __restrict__ cy, const int* __restrict__ cx,
    int* __restrict__ idx_map, int n)
{
    int i = blockIdx.x * blockDim.x + threadIdx.x;
    if (i < n) {
        long cell = ((long)cb[i] * CH + cy[i]) * CW + cx[i];
        atomicMax(&idx_map[cell], i);
    }
}

// ---------------- kernel 2: rulebook: roff[9][n] = row BYTE offsets (idx*64) or -1 --
__global__ __launch_bounds__(256) void k_rulebook(
    const int* __restrict__ cb, const int* __restrict__ cy, const int* __restrict__ cx,
    const int* __restrict__ idx_map, int* __restrict__ roff, int n)
{
    int i = blockIdx.x * blockDim.x + threadIdx.x;
    if (i >= n) return;
    int b = cb[i], y = cy[i], x = cx[i];
    roff[4 * n + i] = idx_map[((long)b * CH + y) * CW + x] * 64;   // self winner >=0
    #pragma unroll
    for (int k = 0; k < 9; ++k) {
        if (k == 4) continue;
        int dy = k / 3 - 1, dx = k % 3 - 1;
        int ny = y + dy, nx = x + dx;
        int nb = -1;
        if (ny >= 0 && ny < CH && nx >= 0 && nx < CW)
            nb = idx_map[((long)b * CH + ny) * CW + nx];
        roff[k * n + i] = (nb >= 0) ? nb * 64 : -1;
    }
}

// ---------------- kernel 3: feats f32 -> bf16 --------------------------------------
__global__ __launch_bounds__(256) void k_cvt(
    const float* __restrict__ f, unsigned short* __restrict__ b, int n32)
{
    int i = (blockIdx.x * 256 + threadIdx.x) * 8;
    if (i + 8 <= n32) {
        float4 a0 = *(const float4*)(f + i);
        float4 a1 = *(const float4*)(f + i + 4);
        uint4 r;
        r.x = pk2(a0.x, a0.y); r.y = pk2(a0.z, a0.w);
        r.z = pk2(a1.x, a1.y); r.w = pk2(a1.z, a1.w);
        *(uint4*)(b + i) = r;
    }
}

// ---------------- kernel 3b: W -> bf16 B-fragments (all 6 layers) + zero rows ------
// Bfg[((layer*9+k)*2+h)*64 + l] = pack8( W[layer][k][ h*16+8*(l>>5)+j ][ l&31 ] )
__global__ __launch_bounds__(256) void k_wcvt(
    const float* __restrict__ Wk, uint4* __restrict__ Bfg,
    unsigned short* __restrict__ z0, unsigned short* __restrict__ z1,
    unsigned short* __restrict__ z2)
{
    if (blockIdx.x == 0 && threadIdx.x < 12) {
        uint4 z = make_uint4(0, 0, 0, 0);
        int tt = threadIdx.x;
        if (tt < 4)       ((uint4*)z0)[tt] = z;
        else if (tt < 8)  ((uint4*)z1)[tt - 4] = z;
        else              ((uint4*)z2)[tt - 8] = z;
    }
    int t = blockIdx.x * 256 + threadIdx.x;
    if (t >= 6 * 9 * 2 * 64) return;
    int l = t & 63, h = (t >> 6) & 1;
    int rest = t >> 7;
    int k = rest % 9, layer = rest / 9;
    int o = l & 31;
    int c0 = h * 16 + 8 * (l >> 5);
    const float* wp = Wk + (size_t)layer * 9216 + k * 1024 + o;   // [c][o], stride 32
    uint4 r;
    r.x = pk2(wp[(c0 + 0) * 32], wp[(c0 + 1) * 32]);
    r.y = pk2(wp[(c0 + 2) * 32], wp[(c0 + 3) * 32]);
    r.z = pk2(wp[(c0 + 4) * 32], wp[(c0 + 5) * 32]);
    r.w = pk2(wp[(c0 + 6) * 32], wp[(c0 + 7) * 32]);
    Bfg[t] = r;
}

// ---------------- kernel 4: gather-K 32x32x16 MFMA conv + BN (+identity) + ReLU ----
// One wave = one 32-point tile. No LDS, no barrier. A: lane l holds row l&31,
// chans 8*(l>>5)..+8 of each K-half (two 16B loads, same vaddr via offset:32).
// B: preconverted frags from global (L2-hot). Invalid/tail rows gather the zeroed
// row n (no cndmask zeroing). D: col=lane&31, row=(reg&3)+8*(reg>>2)+4*(lane>>5).
template<bool ADD_ID, bool F32OUT>
__global__ __launch_bounds__(256, 4) void k_conv(
    const unsigned short* __restrict__ in,   // bf16 [n+1][32], row n = zeros
    const unsigned short* __restrict__ idn,  // bf16 [n][32]
    void* __restrict__ outv,                 // bf16 or f32 [n][32]
    const uint4* __restrict__ Bf,            // [9][2][64] B-frags (this layer)
    const float* __restrict__ bias,
    const float* __restrict__ gamma, const float* __restrict__ beta,
    const float* __restrict__ mean, const float* __restrict__ var,
    const int* __restrict__ roff, int n)
{
    int l = threadIdx.x & 63, wv = threadIdx.x >> 6;
    int q = l & 31, h5 = l >> 5;

    float sc = gamma[q] * rsqrtf(var[q] + EPSV);
    float sh = (bias[q] - mean[q]) * sc + beta[q];

    const int zoff = n * 64;
    const char* inB = (const char*)in;

    int ntile = (n + 31) >> 5;
    for (int tile = blockIdx.x * 4 + wv; tile < ntile; tile += gridDim.x * 4) {
        int p0 = tile << 5;
        int pr = p0 + q;
        bool rowok = pr < n;
        int prc = rowok ? pr : n - 1;

        int rk[9];
        #pragma unroll
        for (int k = 0; k < 9; ++k) rk[k] = roff[(size_t)k * n + prc];

        f32x16 acc = {0.f,0.f,0.f,0.f,0.f,0.f,0.f,0.f,0.f,0.f,0.f,0.f,0.f,0.f,0.f,0.f};
        #pragma unroll
        for (int k = 0; k < 9; ++k) {
            if (__any(rk[k] >= 0)) {
                int off = (rowok && rk[k] >= 0) ? rk[k] : zoff;
                const char* ap = inB + off + h5 * 16;
                U16 a0, a1, b0, b1;
                a0.u = *(const uint4*)(ap);        // chans h5*8   .. +8 (K-half 0)
                a1.u = *(const uint4*)(ap + 32);   // chans 16+h5*8.. +8 (K-half 1)
                b0.u = Bf[(k * 2 + 0) * 64 + l];
                b1.u = Bf[(k * 2 + 1) * 64 + l];
                acc = __builtin_amdgcn_mfma_f32_32x32x16_bf16(a0.v, b0.v, acc, 0, 0, 0);
                acc = __builtin_amdgcn_mfma_f32_32x32x16_bf16(a1.v, b1.v, acc, 0, 0, 0);
            }
        }

        #pragma unroll
        for (int r = 0; r < 16; ++r) {
            int p = p0 + (r & 3) + 8 * (r >> 2) + 4 * h5;
            if (p < n) {
                float y = acc[r] * sc + sh;
                if (ADD_ID) y += b2f(idn[(size_t)p * 32 + q]);
                y = fmaxf(y, 0.f);
                if (F32OUT) ((float*)outv)[(size_t)p * 32 + q] = y;
                else ((unsigned short*)outv)[(size_t)p * 32 + q] = f2b(y);
            }
        }
    }
}

extern "C" void kernel_launch(void* const* d_in, const int* in_sizes, int n_in,
                              void* d_out, int out_size, void* d_ws, size_t ws_size,
                              hipStream_t stream)
{
    const float* feats = (const float*)d_in[0];
    const float* Wk    = (const float*)d_in[1];  // [3][2][9][32][32]
    const float* bias  = (const float*)d_in[2];
    const float* gamma = (const float*)d_in[3];
    const float* beta  = (const float*)d_in[4];
    const float* mean  = (const float*)d_in[5];
    const float* var   = (const float*)d_in[6];
    const int* cb = (const int*)d_in[7];
    const int* cy = (const int*)d_in[8];
    const int* cx = (const int*)d_in[9];
    float* out = (float*)d_out;
    int n = in_sizes[0] / NC;

    char* ws = (char*)d_ws;
    int*            idx_map = (int*)(ws + 0);                   // 33,177,600 B
    int*            roff    = (int*)(ws + 33177600);            //  7,200,000 B
    uint4*          Bfg     = (uint4*)(ws + 40377600);          //    110,592 B
    unsigned short* xbf     = (unsigned short*)(ws + 40488192); // 12,800,064 B
    unsigned short* tmpbf   = (unsigned short*)(ws + 53288256); // 12,800,064 B
    unsigned short* hb      = (unsigned short*)(ws + 66088320); // 12,800,064 B

    int blocks = (n + 255) / 256;
    k_clear<<<blocks, 256, 0, stream>>>(cb, cy, cx, idx_map, n);
    k_build_map<<<blocks, 256, 0, stream>>>(cb, cy, cx, idx_map, n);
    k_rulebook<<<blocks, 256, 0, stream>>>(cb, cy, cx, idx_map, roff, n);
    k_cvt<<<(n * NC / 8 + 255) / 256, 256, 0, stream>>>(feats, xbf, n * NC);
    k_wcvt<<<(6 * 9 * 2 * 64 + 255) / 256, 256, 0, stream>>>(
        Wk, Bfg, xbf + (size_t)n * 32, tmpbf + (size_t)n * 32, hb + (size_t)n * 32);

    const int G = 1024;
    const int BSZ = 9 * 2 * 64; // uint4s per layer of Bfg

    k_conv<false, false><<<G, 256, 0, stream>>>(xbf, nullptr, tmpbf,
        Bfg + 0 * BSZ, bias + 0,  gamma + 0,  beta + 0,  mean + 0,  var + 0,  roff, n);
    k_conv<true,  false><<<G, 256, 0, stream>>>(tmpbf, xbf, hb,
        Bfg + 1 * BSZ, bias + 32, gamma + 32, beta + 32, mean + 32, var + 32, roff, n);
    k_conv<false, false><<<G, 256, 0, stream>>>(hb, nullptr, tmpbf,
        Bfg + 2 * BSZ, bias + 64, gamma + 64, beta + 64, mean + 64, var + 64, roff, n);
    k_conv<true,  false><<<G, 256, 0, stream>>>(tmpbf, hb, xbf,
        Bfg + 3 * BSZ, bias + 96, gamma + 96, beta + 96, mean + 96, var + 96, roff, n);
    k_conv<false, false><<<G, 256, 0, stream>>>(xbf, nullptr, tmpbf,
        Bfg + 4 * BSZ, bias + 128, gamma + 128, beta + 128, mean + 128, var + 128, roff, n);
    k_conv<true,  true><<<G, 256, 0, stream>>>(tmpbf, xbf, out,
        Bfg + 5 * BSZ, bias + 160, gamma + 160, beta + 160, mean + 160, var + 160, roff, n);
}